// Round 7
// baseline (192.727 us; speedup 1.0000x reference)
//
#include <hip/hip_runtime.h>
#include <stdint.h>
#include <stddef.h>

typedef __bf16 bf16;
typedef __bf16 bf16x4 __attribute__((ext_vector_type(4)));
typedef __bf16 bf16x8 __attribute__((ext_vector_type(8)));
typedef float  f32x4  __attribute__((ext_vector_type(4)));
typedef float  f32x16 __attribute__((ext_vector_type(16)));
typedef float  f32x4v __attribute__((ext_vector_type(4)));
typedef unsigned int u32x4 __attribute__((ext_vector_type(4)));

// async global->LDS, 16B per lane, wave-uniform LDS base + lane*16
__device__ __forceinline__ void gload_lds16(const void* g, void* lds) {
  __builtin_amdgcn_global_load_lds(
      (__attribute__((address_space(1))) void*)(uintptr_t)g,
      (__attribute__((address_space(3))) void*)lds,
      16, 0, 0);
}

__device__ __forceinline__ unsigned int pk2(float a, float b) {
  unsigned short lo = __builtin_bit_cast(unsigned short, (bf16)a);
  unsigned short hi = __builtin_bit_cast(unsigned short, (bf16)b);
  return (unsigned int)lo | ((unsigned int)hi << 16);
}

// ---------------- conversion kernels ----------------

__global__ void cvt_f32_to_bf16(const float* __restrict__ in, bf16* __restrict__ out, int n) {
  int i = (blockIdx.x * blockDim.x + threadIdx.x) * 4;
  if (i >= n) return;
  f32x4v v = *reinterpret_cast<const f32x4v*>(in + i);
  bf16x4 o;
  o[0] = (bf16)v[0]; o[1] = (bf16)v[1]; o[2] = (bf16)v[2]; o[3] = (bf16)v[3];
  *reinterpret_cast<bf16x4*>(out + i) = o;
}

// in [R][C] f32  ->  out [C][R] bf16   (R,C multiples of 32)
__global__ void transpose_cvt(const float* __restrict__ in, bf16* __restrict__ out, int R, int C) {
  __shared__ bf16 tile[32][33];
  int c0 = blockIdx.x * 32, r0 = blockIdx.y * 32;
  int tx = threadIdx.x, ty = threadIdx.y;
  #pragma unroll
  for (int i = ty; i < 32; i += 8)
    tile[i][tx] = (bf16)in[(size_t)(r0 + i) * C + (c0 + tx)];
  __syncthreads();
  #pragma unroll
  for (int i = ty; i < 32; i += 8)
    out[(size_t)(c0 + i) * R + (r0 + tx)] = tile[tx][i];
}

// ---------------- GEMM: C[M][N] = A[M][K] * Bt[N][K]^T (+bias) ----------------
// 128x128 tile, BK=64, 4 waves in 2x2, each wave 64x64 (4x4 16x16 fragments).

template <typename OT, bool BIAS>
__global__ __launch_bounds__(256) void gemm_abt(
    const bf16* __restrict__ A,   // [M][K]
    const bf16* __restrict__ Bt,  // [N][K]
    const float* __restrict__ bias,
    OT* __restrict__ C, int M, int N, int K)
{
  __shared__ bf16 As[128 * 64];
  __shared__ bf16 Bs[128 * 64];

  const int tid = threadIdx.x;
  const int w = tid >> 6, l = tid & 63;
  const int l15 = l & 15, l4 = l >> 4, l7 = l & 7;
  const int wr = w >> 1, wc = w & 1;
  const int m0 = blockIdx.y * 128, n0 = blockIdx.x * 128;

  f32x4 acc[4][4];
  #pragma unroll
  for (int i = 0; i < 4; i++)
    #pragma unroll
    for (int j = 0; j < 4; j++) acc[i][j] = (f32x4){0.f, 0.f, 0.f, 0.f};

  const int srow  = w * 8 + (l >> 3);            // + p*32
  const int sslot = (l & 7) ^ ((l >> 3) & 7);    // pre-swizzled 16B slot (row&7 = l>>3)
  const int KT = K >> 6;

  for (int kt = 0; kt < KT; ++kt) {
    __syncthreads();                              // prior compute done reading LDS
    const int kcol = kt * 64 + sslot * 8;
    #pragma unroll
    for (int p = 0; p < 4; ++p) {
      gload_lds16(A  + (size_t)(m0 + p * 32 + srow) * K + kcol,
                  (char*)As + p * 4096 + w * 1024);
      gload_lds16(Bt + (size_t)(n0 + p * 32 + srow) * K + kcol,
                  (char*)Bs + p * 4096 + w * 1024);
    }
    __syncthreads();                              // staging complete (vmcnt drained)

    #pragma unroll
    for (int kk = 0; kk < 2; ++kk) {
      const int coff = (kk * 32 + l4 * 8) ^ (l7 << 3);
      bf16x8 af[4], bq[4];
      #pragma unroll
      for (int m = 0; m < 4; ++m) {
        int r = wr * 64 + m * 16 + l15;           // r&7 == l7
        af[m] = *reinterpret_cast<const bf16x8*>(&As[r * 64 + coff]);
      }
      #pragma unroll
      for (int n = 0; n < 4; ++n) {
        int r = wc * 64 + n * 16 + l15;
        bq[n] = *reinterpret_cast<const bf16x8*>(&Bs[r * 64 + coff]);
      }
      #pragma unroll
      for (int m = 0; m < 4; ++m)
        #pragma unroll
        for (int n = 0; n < 4; ++n)
          acc[m][n] = __builtin_amdgcn_mfma_f32_16x16x32_bf16(af[m], bq[n], acc[m][n], 0, 0, 0);
    }
  }

  // epilogue: D[row][col], col = lane&15, row = (lane>>4)*4 + j
  #pragma unroll
  for (int m = 0; m < 4; ++m) {
    #pragma unroll
    for (int n = 0; n < 4; ++n) {
      int col = n0 + wc * 64 + n * 16 + l15;
      float bv = BIAS ? bias[col] : 0.f;
      #pragma unroll
      for (int j = 0; j < 4; ++j) {
        int row = m0 + wr * 64 + m * 16 + l4 * 4 + j;
        float v = acc[m][n][j] + bv;
        C[(size_t)row * N + col] = (OT)v;
      }
    }
  }
}

// ---------------- fused flash attention (32x32x16, double-buffered) --------
// qkv [8192][3072] bf16. One block = 4 waves, 128 q-rows (32/wave),
// 16 K/V tiles of 64 keys, K/V double-buffered with prefetch:
// per iter: issue V global->reg loads + K global_load_lds for kt+1 (oldest-
// first so the pre-ds_write wait is vmcnt(2), not 0), compute tile kt,
// then transpose-write V(kt+1), one barrier. Fixed-shift softmax (|s|<~2).
// Swapped QK^T: lane holds S^T[key=(reg&3)+8*(reg>>2)+4*hi][q=l31].
// PV is permutation-consistent in-register P (see R6 comment), V B-frags
// read as two ds_read_b64. V slot function c ^ (d&7) ^ ((d>>3)&7) spreads
// the staging writes to the b64 bank minimum (was 8-way conflicted).

__global__ __launch_bounds__(256) void attn_fused(
    const bf16* __restrict__ qkv,
    bf16* __restrict__ aout)      // [8192][1024], col = h*64+d
{
  __shared__ bf16 Ks[2][64 * 64];   // [key][d], source-swizzled 16B slots
  __shared__ bf16 Vt[2][64 * 64];   // [d][key], slot = c ^ (d&7) ^ ((d>>3)&7)

  const int tid = threadIdx.x;
  const int w = tid >> 6, l = tid & 63;
  const int l31 = l & 31, hi = l >> 5;

  // XCD-grouped swizzle: all 8 q-tiles of one (b,h) on one XCD for K/V L2 reuse
  const int bid = blockIdx.x;
  const int c  = bid & 7, rr = bid >> 3;
  const int g  = c * 16 + (rr & 15);     // 0..127 = b*16+h
  const int qt = rr >> 4;                // 0..7
  const int h  = g & 15;
  const int b  = g >> 4;

  const bf16* base = qkv + (size_t)b * 1024 * 3072;
  const int qrow0 = qt * 128 + w * 32;

  // Q B-fragments: qf[st] = Q[qrow0 + l31][st*16 + hi*8 + e], pre-scaled
  const float qscale = 0.03125f * 1.44269504f;   // D^-0.5 * log2(e)
  bf16x8 qf[4];
  #pragma unroll
  for (int st = 0; st < 4; st++) {
    const bf16* p = base + (size_t)(qrow0 + l31) * 3072 + h * 64 + st * 16 + hi * 8;
    bf16x8 v = *reinterpret_cast<const bf16x8*>(p);
    #pragma unroll
    for (int e = 0; e < 8; e++) v[e] = (bf16)((float)v[e] * qscale);
    qf[st] = v;
  }

  bf16x8 onesf;
  #pragma unroll
  for (int e = 0; e < 8; e++) onesf[e] = (bf16)1.0f;

  f32x16 acc0 = {}, acc1 = {}, accS = {};   // dtile 0 / 1 / row-sum

  const int skey  = w * 8 + (l >> 3);            // + p*32
  const int sslot = (l & 7) ^ ((l >> 3) & 7);
  // V quad staging: thread covers keys vk0..vk0+3, d vd0..vd0+3
  const int vd0   = (tid & 15) * 4;
  const int vk0   = (tid >> 4) * 4;
  const int vslot = tid >> 5;                    // 16B slot (key-chunk) of quad
  const int vhalf = (tid >> 4) & 1;              // 8B half

  bf16x4 vv[4];

  // ---- prologue: stage tile 0 into buffer 0 ----
  #pragma unroll
  for (int i = 0; i < 4; ++i)
    vv[i] = *reinterpret_cast<const bf16x4*>(
        base + (size_t)(vk0 + i) * 3072 + 2048 + h * 64 + vd0);
  #pragma unroll
  for (int p = 0; p < 2; ++p)
    gload_lds16(base + (size_t)(p * 32 + skey) * 3072 + 1024 + h * 64 + sslot * 8,
                (char*)Ks[0] + p * 4096 + w * 1024);
  #pragma unroll
  for (int j = 0; j < 4; ++j) {
    int d = vd0 + j;
    bf16x4 o; o[0] = vv[0][j]; o[1] = vv[1][j]; o[2] = vv[2][j]; o[3] = vv[3][j];
    *reinterpret_cast<bf16x4*>(
        &Vt[0][d * 64 + ((vslot ^ (d & 7) ^ ((d >> 3) & 7)) * 8 + vhalf * 4)]) = o;
  }
  __syncthreads();   // drains K gloads (vmcnt) + V ds_writes (lgkm)

  for (int kt = 0; kt < 16; ++kt) {
    const int cur = kt & 1, nxt = cur ^ 1;

    // ---- prefetch tile kt+1: V->regs first (older), then K->LDS ----
    if (kt < 15) {
      #pragma unroll
      for (int i = 0; i < 4; ++i)
        vv[i] = *reinterpret_cast<const bf16x4*>(
            base + (size_t)((kt + 1) * 64 + vk0 + i) * 3072 + 2048 + h * 64 + vd0);
      #pragma unroll
      for (int p = 0; p < 2; ++p)
        gload_lds16(base + (size_t)((kt + 1) * 64 + p * 32 + skey) * 3072 + 1024 + h * 64 + sslot * 8,
                    (char*)Ks[nxt] + p * 4096 + w * 1024);
    }

    // ---- compute on buffer cur ----
    #pragma unroll
    for (int ktile = 0; ktile < 2; ++ktile) {
      // QK^T for 32 keys
      f32x16 s = {};
      const int key = ktile * 32 + l31;
      #pragma unroll
      for (int st = 0; st < 4; ++st) {
        const int slot = (2 * st + hi) ^ (key & 7);
        bf16x8 kf = *reinterpret_cast<const bf16x8*>(&Ks[cur][key * 64 + slot * 8]);
        s = __builtin_amdgcn_mfma_f32_32x32x16_bf16(kf, qf[st], s, 0, 0, 0);
      }
      // P = exp2(s) in place
      #pragma unroll
      for (int r = 0; r < 16; ++r) s[r] = exp2f(s[r]);
      // A-frags in natural reg order (keys pi_hi(e) per 16-key group)
      u32x4 dw0 = {pk2(s[0], s[1]),  pk2(s[2], s[3]),
                   pk2(s[4], s[5]),  pk2(s[6], s[7])};
      u32x4 dw1 = {pk2(s[8], s[9]),  pk2(s[10], s[11]),
                   pk2(s[12], s[13]), pk2(s[14], s[15])};
      bf16x8 pf0 = __builtin_bit_cast(bf16x8, dw0);
      bf16x8 pf1 = __builtin_bit_cast(bf16x8, dw1);

      // row sums (ones-B sums all 16 slots; permutation-invariant)
      accS = __builtin_amdgcn_mfma_f32_32x32x16_bf16(pf0, onesf, accS, 0, 0, 0);
      accS = __builtin_amdgcn_mfma_f32_32x32x16_bf16(pf1, onesf, accS, 0, 0, 0);

      // O += P V with pi-ordered V B-frags (two b64 reads per row)
      const int d7x0 = (l31 & 7) ^ (l31 >> 3);        // dtile0 slot XOR
      const int d7x1 = d7x0 ^ 4;                      // dtile1: (d>>3)&7 gains +4
      #pragma unroll
      for (int gg = 0; gg < 2; ++gg) {
        bf16x8 pf = gg ? pf1 : pf0;
        const int cb = ktile * 4 + gg * 2;
        bf16x4 a0 = *reinterpret_cast<const bf16x4*>(
            &Vt[cur][l31 * 64 + (((cb) ^ d7x0) * 8 + hi * 4)]);
        bf16x4 b0 = *reinterpret_cast<const bf16x4*>(
            &Vt[cur][l31 * 64 + (((cb + 1) ^ d7x0) * 8 + hi * 4)]);
        bf16x8 vf0;
        #pragma unroll
        for (int e = 0; e < 4; ++e) { vf0[e] = a0[e]; vf0[4 + e] = b0[e]; }
        acc0 = __builtin_amdgcn_mfma_f32_32x32x16_bf16(pf, vf0, acc0, 0, 0, 0);

        bf16x4 a1 = *reinterpret_cast<const bf16x4*>(
            &Vt[cur][(32 + l31) * 64 + (((cb) ^ d7x1) * 8 + hi * 4)]);
        bf16x4 b1 = *reinterpret_cast<const bf16x4*>(
            &Vt[cur][(32 + l31) * 64 + (((cb + 1) ^ d7x1) * 8 + hi * 4)]);
        bf16x8 vf1;
        #pragma unroll
        for (int e = 0; e < 4; ++e) { vf1[e] = a1[e]; vf1[4 + e] = b1[e]; }
        acc1 = __builtin_amdgcn_mfma_f32_32x32x16_bf16(pf, vf1, acc1, 0, 0, 0);
      }
    }

    // ---- late half of staging: V transpose-write for kt+1 ----
    if (kt < 15) {
      #pragma unroll
      for (int j = 0; j < 4; ++j) {
        int d = vd0 + j;
        bf16x4 o; o[0] = vv[0][j]; o[1] = vv[1][j]; o[2] = vv[2][j]; o[3] = vv[3][j];
        *reinterpret_cast<bf16x4*>(
            &Vt[nxt][d * 64 + ((vslot ^ (d & 7) ^ ((d >> 3) & 7)) * 8 + vhalf * 4)]) = o;
      }
    }
    __syncthreads();   // staging of kt+1 complete; cur buffer free
  }

  // epilogue: row q = (reg&3)+8*(reg>>2)+4*hi, col = l31 (+32 for dtile 1);
  // accS[reg] = full row sum (identical across cols) -> no shuffles
  #pragma unroll
  for (int reg = 0; reg < 16; ++reg) {
    int q_r = (reg & 3) + 8 * (reg >> 2) + 4 * hi;
    float rinv = 1.0f / accS[reg];
    size_t rowoff = ((size_t)b * 1024 + qrow0 + q_r) * 1024 + h * 64;
    aout[rowoff + l31]      = (bf16)(acc0[reg] * rinv);
    aout[rowoff + 32 + l31] = (bf16)(acc1[reg] * rinv);
  }
}

// ---------------- launch ----------------

extern "C" void kernel_launch(void* const* d_in, const int* in_sizes, int n_in,
                              void* d_out, int out_size, void* d_ws, size_t ws_size,
                              hipStream_t stream) {
  const float* x     = (const float*)d_in[0];   // [8,1024,1024]
  const float* w_in  = (const float*)d_in[1];   // [1024,3072]
  const float* w_out = (const float*)d_in[2];   // [1024,1024]
  const float* b_out = (const float*)d_in[3];   // [1024]
  float* out = (float*)d_out;                   // [8,1024,1024] fp32

  bf16* xb    = (bf16*)d_ws;                         // 8192*1024
  bf16* wint  = xb    + (size_t)8192 * 1024;         // 3072*1024  (w_in^T)
  bf16* woutt = wint  + (size_t)3072 * 1024;         // 1024*1024  (w_out^T)
  bf16* qkv   = woutt + (size_t)1024 * 1024;         // 8192*3072
  bf16* ao    = qkv   + (size_t)8192 * 3072;         // 8192*1024

  cvt_f32_to_bf16<<<8192, 256, 0, stream>>>(x, xb, 8192 * 1024);
  transpose_cvt<<<dim3(96, 32), dim3(32, 8), 0, stream>>>(w_in,  wint,  1024, 3072);
  transpose_cvt<<<dim3(32, 32), dim3(32, 8), 0, stream>>>(w_out, woutt, 1024, 1024);

  // qkv = x @ w_in   (bf16 out)
  gemm_abt<bf16, false><<<dim3(24, 64), 256, 0, stream>>>(xb, wint, nullptr, qkv, 8192, 3072, 1024);

  // fused attention -> ao (bf16, [token][h*64+d])
  attn_fused<<<1024, 256, 0, stream>>>(qkv, ao);

  // out = ao @ w_out + b_out   (fp32 out)
  gemm_abt<float, true><<<dim3(8, 64), 256, 0, stream>>>(ao, woutt, b_out, out, 8192, 1024, 1024);
}

// Round 8
// 173.132 us; speedup vs baseline: 1.1132x; 1.1132x over previous
//
#include <hip/hip_runtime.h>
#include <stdint.h>
#include <stddef.h>

typedef __bf16 bf16;
typedef __bf16 bf16x4 __attribute__((ext_vector_type(4)));
typedef __bf16 bf16x8 __attribute__((ext_vector_type(8)));
typedef float  f32x4  __attribute__((ext_vector_type(4)));
typedef float  f32x16 __attribute__((ext_vector_type(16)));
typedef float  f32x4v __attribute__((ext_vector_type(4)));

// async global->LDS, 16B per lane, wave-uniform LDS base + lane*16
__device__ __forceinline__ void gload_lds16(const void* g, void* lds) {
  __builtin_amdgcn_global_load_lds(
      (__attribute__((address_space(1))) void*)(uintptr_t)g,
      (__attribute__((address_space(3))) void*)lds,
      16, 0, 0);
}

// ---------------- conversion kernels ----------------

__global__ void cvt_f32_to_bf16(const float* __restrict__ in, bf16* __restrict__ out, int n) {
  int i = (blockIdx.x * blockDim.x + threadIdx.x) * 4;
  if (i >= n) return;
  f32x4v v = *reinterpret_cast<const f32x4v*>(in + i);
  bf16x4 o;
  o[0] = (bf16)v[0]; o[1] = (bf16)v[1]; o[2] = (bf16)v[2]; o[3] = (bf16)v[3];
  *reinterpret_cast<bf16x4*>(out + i) = o;
}

// in [R][C] f32  ->  out [C][R] bf16   (R,C multiples of 32)
__global__ void transpose_cvt(const float* __restrict__ in, bf16* __restrict__ out, int R, int C) {
  __shared__ bf16 tile[32][33];
  int c0 = blockIdx.x * 32, r0 = blockIdx.y * 32;
  int tx = threadIdx.x, ty = threadIdx.y;
  #pragma unroll
  for (int i = ty; i < 32; i += 8)
    tile[i][tx] = (bf16)in[(size_t)(r0 + i) * C + (c0 + tx)];
  __syncthreads();
  #pragma unroll
  for (int i = ty; i < 32; i += 8)
    out[(size_t)(c0 + i) * R + (r0 + tx)] = tile[tx][i];
}

// ---------------- GEMM: C[M][N] = A[M][K] * Bt[N][K]^T (+bias) ----------------
// 128x128 tile, BK=64, 4 waves in 2x2, each wave 64x64 (4x4 16x16 fragments).

template <typename OT, bool BIAS>
__global__ __launch_bounds__(256) void gemm_abt(
    const bf16* __restrict__ A,   // [M][K]
    const bf16* __restrict__ Bt,  // [N][K]
    const float* __restrict__ bias,
    OT* __restrict__ C, int M, int N, int K)
{
  __shared__ bf16 As[128 * 64];
  __shared__ bf16 Bs[128 * 64];

  const int tid = threadIdx.x;
  const int w = tid >> 6, l = tid & 63;
  const int l15 = l & 15, l4 = l >> 4, l7 = l & 7;
  const int wr = w >> 1, wc = w & 1;
  const int m0 = blockIdx.y * 128, n0 = blockIdx.x * 128;

  f32x4 acc[4][4];
  #pragma unroll
  for (int i = 0; i < 4; i++)
    #pragma unroll
    for (int j = 0; j < 4; j++) acc[i][j] = (f32x4){0.f, 0.f, 0.f, 0.f};

  const int srow  = w * 8 + (l >> 3);            // + p*32
  const int sslot = (l & 7) ^ ((l >> 3) & 7);    // pre-swizzled 16B slot (row&7 = l>>3)
  const int KT = K >> 6;

  for (int kt = 0; kt < KT; ++kt) {
    __syncthreads();                              // prior compute done reading LDS
    const int kcol = kt * 64 + sslot * 8;
    #pragma unroll
    for (int p = 0; p < 4; ++p) {
      gload_lds16(A  + (size_t)(m0 + p * 32 + srow) * K + kcol,
                  (char*)As + p * 4096 + w * 1024);
      gload_lds16(Bt + (size_t)(n0 + p * 32 + srow) * K + kcol,
                  (char*)Bs + p * 4096 + w * 1024);
    }
    __syncthreads();                              // staging complete (vmcnt drained)

    #pragma unroll
    for (int kk = 0; kk < 2; ++kk) {
      const int coff = (kk * 32 + l4 * 8) ^ (l7 << 3);
      bf16x8 af[4], bq[4];
      #pragma unroll
      for (int m = 0; m < 4; ++m) {
        int r = wr * 64 + m * 16 + l15;           // r&7 == l7
        af[m] = *reinterpret_cast<const bf16x8*>(&As[r * 64 + coff]);
      }
      #pragma unroll
      for (int n = 0; n < 4; ++n) {
        int r = wc * 64 + n * 16 + l15;
        bq[n] = *reinterpret_cast<const bf16x8*>(&Bs[r * 64 + coff]);
      }
      #pragma unroll
      for (int m = 0; m < 4; ++m)
        #pragma unroll
        for (int n = 0; n < 4; ++n)
          acc[m][n] = __builtin_amdgcn_mfma_f32_16x16x32_bf16(af[m], bq[n], acc[m][n], 0, 0, 0);
    }
  }

  // epilogue: D[row][col], col = lane&15, row = (lane>>4)*4 + j
  #pragma unroll
  for (int m = 0; m < 4; ++m) {
    #pragma unroll
    for (int n = 0; n < 4; ++n) {
      int col = n0 + wc * 64 + n * 16 + l15;
      float bv = BIAS ? bias[col] : 0.f;
      #pragma unroll
      for (int j = 0; j < 4; ++j) {
        int row = m0 + wr * 64 + m * 16 + l4 * 4 + j;
        float v = acc[m][n][j] + bv;
        C[(size_t)row * N + col] = (OT)v;
      }
    }
  }
}

// ---------------- fused flash attention (32x32x16, R5 structure) -----------
// qkv [8192][3072] bf16. One block = 4 waves, 128 q-rows (32/wave),
// 16 K/V tiles of 64 keys, single-buffered (best measured; dbuf and
// in-register P both regressed - occupancy/VGPR-bound, not staging-bound).
// Fixed-shift softmax (|s|<~2, exact by shift invariance).
// Swapped QK^T: lane holds S^T[key=(reg&3)+8*(reg>>2)+4*hi][q=l31].
// P via per-wave LDS (packed b64 writes, chunk^(q&7) slot swizzle).
// exp2 via __builtin_amdgcn_exp2f: single v_exp_f32, no denormal fixup
// (~4 VALU ops saved per element; biggest VALU item in the loop).
// V swizzle c ^ (d&7) ^ ((d>>3)&7) (R7-verified, halves bank conflicts).
// Row sums via ones-B MFMA into accS (R6-verified): kills 32 adds/tile
// and the epilogue shuffle redistribution; denominators match PV's bf16 P.

__global__ __launch_bounds__(256) void attn_fused(
    const bf16* __restrict__ qkv,
    bf16* __restrict__ aout)      // [8192][1024], col = h*64+d
{
  __shared__ bf16 Ks[64 * 64];      // [key][d], source-swizzled 16B slots
  __shared__ bf16 Vt[64 * 64];      // [d][key], slot = c ^ (d&7) ^ ((d>>3)&7)
  __shared__ bf16 Pl[4][32 * 64];   // per-wave P [q][key], slot = c ^ (q&7)

  const int tid = threadIdx.x;
  const int w = tid >> 6, l = tid & 63;
  const int l31 = l & 31, hi = l >> 5;

  // XCD-grouped swizzle: all 8 q-tiles of one (b,h) on one XCD for K/V L2 reuse
  const int bid = blockIdx.x;
  const int c  = bid & 7, rr = bid >> 3;
  const int g  = c * 16 + (rr & 15);     // 0..127 = b*16+h
  const int qt = rr >> 4;                // 0..7
  const int h  = g & 15;
  const int b  = g >> 4;

  const bf16* base = qkv + (size_t)b * 1024 * 3072;
  const int qrow0 = qt * 128 + w * 32;

  // Q B-fragments: qf[st] = Q[qrow0 + l31][st*16 + hi*8 + e], pre-scaled
  const float qscale = 0.03125f * 1.44269504f;   // D^-0.5 * log2(e)
  bf16x8 qf[4];
  #pragma unroll
  for (int st = 0; st < 4; st++) {
    const bf16* p = base + (size_t)(qrow0 + l31) * 3072 + h * 64 + st * 16 + hi * 8;
    bf16x8 v = *reinterpret_cast<const bf16x8*>(p);
    #pragma unroll
    for (int e = 0; e < 8; e++) v[e] = (bf16)((float)v[e] * qscale);
    qf[st] = v;
  }

  bf16x8 onesf;
  #pragma unroll
  for (int e = 0; e < 8; e++) onesf[e] = (bf16)1.0f;

  f32x16 acc0 = {}, acc1 = {}, accS = {};   // dtile 0 / 1 / row-sum

  const int skey  = w * 8 + (l >> 3);            // + p*32
  const int sslot = (l & 7) ^ ((l >> 3) & 7);
  // V quad staging: thread covers keys vk0..vk0+3, d vd0..vd0+3
  const int vd0   = (tid & 15) * 4;
  const int vk0   = (tid >> 4) * 4;
  const int vslot = tid >> 5;                    // 16B slot (key-chunk) of quad
  const int vhalf = (tid >> 4) & 1;              // 8B half

  for (int kt = 0; kt < 16; ++kt) {
    __syncthreads();
    // K tile -> LDS (async, pre-swizzled source column)
    #pragma unroll
    for (int p = 0; p < 2; ++p)
      gload_lds16(base + (size_t)(kt * 64 + p * 32 + skey) * 3072 + 1024 + h * 64 + sslot * 8,
                  (char*)Ks + p * 4096 + w * 1024);
    // V tile: 4x4 quad -> register transpose -> packed b64 LDS writes
    {
      bf16x4 vv[4];
      #pragma unroll
      for (int i = 0; i < 4; ++i)
        vv[i] = *reinterpret_cast<const bf16x4*>(
            base + (size_t)(kt * 64 + vk0 + i) * 3072 + 2048 + h * 64 + vd0);
      #pragma unroll
      for (int j = 0; j < 4; ++j) {
        int d = vd0 + j;
        bf16x4 o; o[0] = vv[0][j]; o[1] = vv[1][j]; o[2] = vv[2][j]; o[3] = vv[3][j];
        *reinterpret_cast<bf16x4*>(
            &Vt[d * 64 + ((vslot ^ (d & 7) ^ ((d >> 3) & 7)) * 8 + vhalf * 4)]) = o;
      }
    }
    __syncthreads();

    // QK^T per 32-key subtile; P = exp2(S) -> per-wave LDS (packed b64)
    #pragma unroll
    for (int ktile = 0; ktile < 2; ++ktile) {
      f32x16 s = {};
      const int key = ktile * 32 + l31;
      #pragma unroll
      for (int st = 0; st < 4; ++st) {
        const int slot = (2 * st + hi) ^ (key & 7);
        bf16x8 kf = *reinterpret_cast<const bf16x8*>(&Ks[key * 64 + slot * 8]);
        s = __builtin_amdgcn_mfma_f32_32x32x16_bf16(kf, qf[st], s, 0, 0, 0);
      }
      // lane holds S[key = ktile*32 + (reg&3)+8*(reg>>2)+4*hi][q = l31]:
      // reg quad gq gives 4 contiguous keys ktile*32 + 8*gq + 4*hi + (0..3)
      #pragma unroll
      for (int gq = 0; gq < 4; ++gq) {
        bf16x4 pb;
        #pragma unroll
        for (int j2 = 0; j2 < 4; ++j2) {
          float pv = __builtin_amdgcn_exp2f(s[4 * gq + j2]);
          pb[j2] = (bf16)pv;
        }
        const int chunk = ktile * 4 + gq;        // 8-key chunk index
        *reinterpret_cast<bf16x4*>(
            &Pl[w][l31 * 64 + ((chunk ^ (l31 & 7)) * 8 + hi * 4)]) = pb;
      }
    }

    // O += P V  (A-frag: P[q=l31][k=st*16+hi*8+e]; B-frag: V[k][d=l31(+32)])
    const int d7x0 = (l31 & 7) ^ (l31 >> 3);      // dtile0 slot XOR
    const int d7x1 = d7x0 ^ 4;                    // dtile1: (d>>3)&7 gains +4
    #pragma unroll
    for (int st = 0; st < 4; ++st) {
      const int cs = 2 * st + hi;
      bf16x8 pa  = *reinterpret_cast<const bf16x8*>(
          &Pl[w][l31 * 64 + ((cs ^ (l31 & 7)) * 8)]);
      accS = __builtin_amdgcn_mfma_f32_32x32x16_bf16(pa, onesf, accS, 0, 0, 0);
      bf16x8 vf0 = *reinterpret_cast<const bf16x8*>(
          &Vt[l31 * 64 + ((cs ^ d7x0) * 8)]);
      acc0 = __builtin_amdgcn_mfma_f32_32x32x16_bf16(pa, vf0, acc0, 0, 0, 0);
      bf16x8 vf1 = *reinterpret_cast<const bf16x8*>(
          &Vt[(32 + l31) * 64 + ((cs ^ d7x1) * 8)]);
      acc1 = __builtin_amdgcn_mfma_f32_32x32x16_bf16(pa, vf1, acc1, 0, 0, 0);
    }
  }

  // epilogue: row q = (reg&3)+8*(reg>>2)+4*hi, col = l31 (+32 for dtile 1);
  // accS[reg] = full row sum (identical across cols) -> no shuffles
  #pragma unroll
  for (int reg = 0; reg < 16; ++reg) {
    int q_r = (reg & 3) + 8 * (reg >> 2) + 4 * hi;
    float rinv = 1.0f / accS[reg];
    size_t rowoff = ((size_t)b * 1024 + qrow0 + q_r) * 1024 + h * 64;
    aout[rowoff + l31]      = (bf16)(acc0[reg] * rinv);
    aout[rowoff + 32 + l31] = (bf16)(acc1[reg] * rinv);
  }
}

// ---------------- launch ----------------

extern "C" void kernel_launch(void* const* d_in, const int* in_sizes, int n_in,
                              void* d_out, int out_size, void* d_ws, size_t ws_size,
                              hipStream_t stream) {
  const float* x     = (const float*)d_in[0];   // [8,1024,1024]
  const float* w_in  = (const float*)d_in[1];   // [1024,3072]
  const float* w_out = (const float*)d_in[2];   // [1024,1024]
  const float* b_out = (const float*)d_in[3];   // [1024]
  float* out = (float*)d_out;                   // [8,1024,1024] fp32

  bf16* xb    = (bf16*)d_ws;                         // 8192*1024
  bf16* wint  = xb    + (size_t)8192 * 1024;         // 3072*1024  (w_in^T)
  bf16* woutt = wint  + (size_t)3072 * 1024;         // 1024*1024  (w_out^T)
  bf16* qkv   = woutt + (size_t)1024 * 1024;         // 8192*3072
  bf16* ao    = qkv   + (size_t)8192 * 3072;         // 8192*1024

  cvt_f32_to_bf16<<<8192, 256, 0, stream>>>(x, xb, 8192 * 1024);
  transpose_cvt<<<dim3(96, 32), dim3(32, 8), 0, stream>>>(w_in,  wint,  1024, 3072);
  transpose_cvt<<<dim3(32, 32), dim3(32, 8), 0, stream>>>(w_out, woutt, 1024, 1024);

  // qkv = x @ w_in   (bf16 out)
  gemm_abt<bf16, false><<<dim3(24, 64), 256, 0, stream>>>(xb, wint, nullptr, qkv, 8192, 3072, 1024);

  // fused attention -> ao (bf16, [token][h*64+d])
  attn_fused<<<1024, 256, 0, stream>>>(qkv, ao);

  // out = ao @ w_out + b_out   (fp32 out)
  gemm_abt<float, true><<<dim3(8, 64), 256, 0, stream>>>(ao, woutt, b_out, out, 8192, 1024, 1024);
}

// Round 9
// 171.744 us; speedup vs baseline: 1.1222x; 1.0081x over previous
//
#include <hip/hip_runtime.h>
#include <stdint.h>
#include <stddef.h>

typedef __bf16 bf16;
typedef __bf16 bf16x4 __attribute__((ext_vector_type(4)));
typedef __bf16 bf16x8 __attribute__((ext_vector_type(8)));
typedef float  f32x4  __attribute__((ext_vector_type(4)));
typedef float  f32x16 __attribute__((ext_vector_type(16)));
typedef float  f32x4v __attribute__((ext_vector_type(4)));

// async global->LDS, 16B per lane, wave-uniform LDS base + lane*16
__device__ __forceinline__ void gload_lds16(const void* g, void* lds) {
  __builtin_amdgcn_global_load_lds(
      (__attribute__((address_space(1))) void*)(uintptr_t)g,
      (__attribute__((address_space(3))) void*)lds,
      16, 0, 0);
}

// ---------------- conversion kernels ----------------

__global__ void cvt_f32_to_bf16(const float* __restrict__ in, bf16* __restrict__ out, int n) {
  int i = (blockIdx.x * blockDim.x + threadIdx.x) * 4;
  if (i >= n) return;
  f32x4v v = *reinterpret_cast<const f32x4v*>(in + i);
  bf16x4 o;
  o[0] = (bf16)v[0]; o[1] = (bf16)v[1]; o[2] = (bf16)v[2]; o[3] = (bf16)v[3];
  *reinterpret_cast<bf16x4*>(out + i) = o;
}

// in [R][C] f32  ->  out [C][R] bf16   (R,C multiples of 32)
__global__ void transpose_cvt(const float* __restrict__ in, bf16* __restrict__ out, int R, int C) {
  __shared__ bf16 tile[32][33];
  int c0 = blockIdx.x * 32, r0 = blockIdx.y * 32;
  int tx = threadIdx.x, ty = threadIdx.y;
  #pragma unroll
  for (int i = ty; i < 32; i += 8)
    tile[i][tx] = (bf16)in[(size_t)(r0 + i) * C + (c0 + tx)];
  __syncthreads();
  #pragma unroll
  for (int i = ty; i < 32; i += 8)
    out[(size_t)(c0 + i) * R + (r0 + tx)] = tile[tx][i];
}

// ---------------- GEMM 128^2 (2-barrier m97 structure) ----------------
// kept for GEMM2 (N=1024 -> 512 blocks; 256^2 would leave half the CUs idle)

template <typename OT, bool BIAS>
__global__ __launch_bounds__(256) void gemm_abt(
    const bf16* __restrict__ A,   // [M][K]
    const bf16* __restrict__ Bt,  // [N][K]
    const float* __restrict__ bias,
    OT* __restrict__ C, int M, int N, int K)
{
  __shared__ bf16 As[128 * 64];
  __shared__ bf16 Bs[128 * 64];

  const int tid = threadIdx.x;
  const int w = tid >> 6, l = tid & 63;
  const int l15 = l & 15, l4 = l >> 4, l7 = l & 7;
  const int wr = w >> 1, wc = w & 1;
  const int m0 = blockIdx.y * 128, n0 = blockIdx.x * 128;

  f32x4 acc[4][4];
  #pragma unroll
  for (int i = 0; i < 4; i++)
    #pragma unroll
    for (int j = 0; j < 4; j++) acc[i][j] = (f32x4){0.f, 0.f, 0.f, 0.f};

  const int srow  = w * 8 + (l >> 3);            // + p*32
  const int sslot = (l & 7) ^ ((l >> 3) & 7);    // pre-swizzled 16B slot (row&7 = l>>3)
  const int KT = K >> 6;

  for (int kt = 0; kt < KT; ++kt) {
    __syncthreads();
    const int kcol = kt * 64 + sslot * 8;
    #pragma unroll
    for (int p = 0; p < 4; ++p) {
      gload_lds16(A  + (size_t)(m0 + p * 32 + srow) * K + kcol,
                  (char*)As + p * 4096 + w * 1024);
      gload_lds16(Bt + (size_t)(n0 + p * 32 + srow) * K + kcol,
                  (char*)Bs + p * 4096 + w * 1024);
    }
    __syncthreads();

    #pragma unroll
    for (int kk = 0; kk < 2; ++kk) {
      const int coff = (kk * 32 + l4 * 8) ^ (l7 << 3);
      bf16x8 af[4], bq[4];
      #pragma unroll
      for (int m = 0; m < 4; ++m) {
        int r = wr * 64 + m * 16 + l15;
        af[m] = *reinterpret_cast<const bf16x8*>(&As[r * 64 + coff]);
      }
      #pragma unroll
      for (int n = 0; n < 4; ++n) {
        int r = wc * 64 + n * 16 + l15;
        bq[n] = *reinterpret_cast<const bf16x8*>(&Bs[r * 64 + coff]);
      }
      #pragma unroll
      for (int m = 0; m < 4; ++m)
        #pragma unroll
        for (int n = 0; n < 4; ++n)
          acc[m][n] = __builtin_amdgcn_mfma_f32_16x16x32_bf16(af[m], bq[n], acc[m][n], 0, 0, 0);
    }
  }

  #pragma unroll
  for (int m = 0; m < 4; ++m) {
    #pragma unroll
    for (int n = 0; n < 4; ++n) {
      int col = n0 + wc * 64 + n * 16 + l15;
      float bv = BIAS ? bias[col] : 0.f;
      #pragma unroll
      for (int j = 0; j < 4; ++j) {
        int row = m0 + wr * 64 + m * 16 + l4 * 4 + j;
        float v = acc[m][n][j] + bv;
        C[(size_t)row * N + col] = (OT)v;
      }
    }
  }
}

// ---------------- GEMM 256^2 8-wave phase-interleaved (T2+T3+T4+T5) --------
// 512 threads = 8 waves (2M x 4N), per-wave 128x64 output (8x4 16x16 frags).
// BK=64, double-buffered LDS (128 KiB). Per K-tile, 4 phases:
//   {ds_read frags ; stage (phases 0-1) ; s_barrier ; setprio(1) ;
//    16 MFMA ; setprio(0) ; [vmcnt(0) at phase 3] ; s_barrier}
// Staging for tile t+1 is issued in phases 0-1 of tile t and drained ONCE
// (own-wave vmcnt(0) before the tile-boundary barrier -> after the barrier
// every wave's loads are complete). Loads get >=2 phases of MFMA to land,
// unlike the m97 structure's issue-then-drain. Same both-sides 16B-slot
// XOR swizzle as the 128^2 kernel (measured bank-conflict 0).

template <typename OT, bool BIAS>
__global__ __launch_bounds__(512) void gemm_abt8(
    const bf16* __restrict__ A,   // [M][K]
    const bf16* __restrict__ Bt,  // [N][K]
    const float* __restrict__ bias,
    OT* __restrict__ C, int M, int N, int K)
{
  __shared__ bf16 As[2][256 * 64];
  __shared__ bf16 Bs[2][256 * 64];

  const int tid = threadIdx.x;
  const int w = tid >> 6, l = tid & 63;
  const int l15 = l & 15, l4 = l >> 4, l7 = l & 7;
  const int wm = w >> 2, wn = w & 3;

  // XCD-chunked bid swizzle (bijective: grid % 8 == 0): 8 chunks of
  // consecutive tiles -> A-panel reuse inside one XCD's L2.
  const int nwgx = N >> 8;
  const int nwg  = (M >> 8) * nwgx;
  const int cpx  = nwg >> 3;
  const int bid  = blockIdx.x;
  const int swz  = (bid & 7) * cpx + (bid >> 3);
  const int m0 = (swz / nwgx) * 256, n0 = (swz % nwgx) * 256;

  f32x4 acc[8][4];
  #pragma unroll
  for (int i = 0; i < 8; i++)
    #pragma unroll
    for (int j = 0; j < 4; j++) acc[i][j] = (f32x4){0.f, 0.f, 0.f, 0.f};

  const int w8l   = w * 8 + (l >> 3);            // staging row 0..63 (+p*64)
  const int sslot = (l & 7) ^ ((l >> 3) & 7);    // pre-swizzled 16B slot
  const int KT = K >> 6;

  // prologue: stage tile 0 -> buf 0 (A: 4 gloads, B: 4 gloads)
  {
    const int kcol = sslot * 8;
    #pragma unroll
    for (int p = 0; p < 4; ++p) {
      gload_lds16(A  + (size_t)(m0 + p * 64 + w8l) * K + kcol,
                  (char*)As[0] + p * 8192 + w * 1024);
      gload_lds16(Bt + (size_t)(n0 + p * 64 + w8l) * K + kcol,
                  (char*)Bs[0] + p * 8192 + w * 1024);
    }
  }
  asm volatile("s_waitcnt vmcnt(0)" ::: "memory");
  __builtin_amdgcn_s_barrier();

  for (int t = 0; t < KT; ++t) {
    const int cur = t & 1, nxt = cur ^ 1;
    const bf16* as = As[cur];
    const bf16* bs = Bs[cur];
    const int kcol = (t + 1) * 64 + sslot * 8;
    const bool pre = (t < KT - 1);

    bf16x8 afr[4][2];
    bf16x8 bfr[2][2];

    #pragma unroll
    for (int ph = 0; ph < 4; ++ph) {
      const int mh = ph >> 1, nh = ph & 1;

      // ---- ds_read fragments for this phase ----
      if (nh == 0) {
        #pragma unroll
        for (int i = 0; i < 4; ++i)
          #pragma unroll
          for (int kk = 0; kk < 2; ++kk)
            afr[i][kk] = *reinterpret_cast<const bf16x8*>(
                &as[wm * 8192 + ((mh * 4 + i) * 16 + l15) * 64 + (((kk * 4 + l4) ^ l7) * 8)]);
      }
      #pragma unroll
      for (int n2 = 0; n2 < 2; ++n2)
        #pragma unroll
        for (int kk = 0; kk < 2; ++kk)
          bfr[n2][kk] = *reinterpret_cast<const bf16x8*>(
              &bs[(wn >> 1) * 8192 + ((wn & 1) * 64 + (nh * 2 + n2) * 16 + l15) * 64
                  + (((kk * 4 + l4) ^ l7) * 8)]);

      // ---- stage tile t+1 (A in phase 0, B in phase 1) ----
      if (pre && ph == 0) {
        #pragma unroll
        for (int p = 0; p < 4; ++p)
          gload_lds16(A + (size_t)(m0 + p * 64 + w8l) * K + kcol,
                      (char*)As[nxt] + p * 8192 + w * 1024);
      }
      if (pre && ph == 1) {
        #pragma unroll
        for (int p = 0; p < 4; ++p)
          gload_lds16(Bt + (size_t)(n0 + p * 64 + w8l) * K + kcol,
                      (char*)Bs[nxt] + p * 8192 + w * 1024);
      }

      __builtin_amdgcn_s_barrier();
      __builtin_amdgcn_s_setprio(1);
      #pragma unroll
      for (int i = 0; i < 4; ++i)
        #pragma unroll
        for (int n2 = 0; n2 < 2; ++n2)
          #pragma unroll
          for (int kk = 0; kk < 2; ++kk)
            acc[mh * 4 + i][nh * 2 + n2] = __builtin_amdgcn_mfma_f32_16x16x32_bf16(
                afr[i][kk], bfr[n2][kk], acc[mh * 4 + i][nh * 2 + n2], 0, 0, 0);
      __builtin_amdgcn_s_setprio(0);
      if (ph == 3) {
        // own-wave drain of tile t+1 staging; barrier publishes to all waves
        asm volatile("s_waitcnt vmcnt(0)" ::: "memory");
      }
      __builtin_amdgcn_s_barrier();
    }
  }

  // epilogue: D[row][col], col = lane&15, row = (lane>>4)*4 + j
  #pragma unroll
  for (int mf = 0; mf < 8; ++mf) {
    #pragma unroll
    for (int nf = 0; nf < 4; ++nf) {
      int col = n0 + wn * 64 + nf * 16 + l15;
      float bv = BIAS ? bias[col] : 0.f;
      #pragma unroll
      for (int j = 0; j < 4; ++j) {
        int row = m0 + wm * 128 + mf * 16 + l4 * 4 + j;
        float v = acc[mf][nf][j] + bv;
        C[(size_t)row * N + col] = (OT)v;
      }
    }
  }
}

// ---------------- fused flash attention (32x32x16, R5 structure) -----------
// (unchanged from R8 - see prior round comments)

__global__ __launch_bounds__(256) void attn_fused(
    const bf16* __restrict__ qkv,
    bf16* __restrict__ aout)      // [8192][1024], col = h*64+d
{
  __shared__ bf16 Ks[64 * 64];      // [key][d], source-swizzled 16B slots
  __shared__ bf16 Vt[64 * 64];      // [d][key], slot = c ^ (d&7) ^ ((d>>3)&7)
  __shared__ bf16 Pl[4][32 * 64];   // per-wave P [q][key], slot = c ^ (q&7)

  const int tid = threadIdx.x;
  const int w = tid >> 6, l = tid & 63;
  const int l31 = l & 31, hi = l >> 5;

  const int bid = blockIdx.x;
  const int c  = bid & 7, rr = bid >> 3;
  const int g  = c * 16 + (rr & 15);     // 0..127 = b*16+h
  const int qt = rr >> 4;                // 0..7
  const int h  = g & 15;
  const int b  = g >> 4;

  const bf16* base = qkv + (size_t)b * 1024 * 3072;
  const int qrow0 = qt * 128 + w * 32;

  const float qscale = 0.03125f * 1.44269504f;   // D^-0.5 * log2(e)
  bf16x8 qf[4];
  #pragma unroll
  for (int st = 0; st < 4; st++) {
    const bf16* p = base + (size_t)(qrow0 + l31) * 3072 + h * 64 + st * 16 + hi * 8;
    bf16x8 v = *reinterpret_cast<const bf16x8*>(p);
    #pragma unroll
    for (int e = 0; e < 8; e++) v[e] = (bf16)((float)v[e] * qscale);
    qf[st] = v;
  }

  bf16x8 onesf;
  #pragma unroll
  for (int e = 0; e < 8; e++) onesf[e] = (bf16)1.0f;

  f32x16 acc0 = {}, acc1 = {}, accS = {};

  const int skey  = w * 8 + (l >> 3);
  const int sslot = (l & 7) ^ ((l >> 3) & 7);
  const int vd0   = (tid & 15) * 4;
  const int vk0   = (tid >> 4) * 4;
  const int vslot = tid >> 5;
  const int vhalf = (tid >> 4) & 1;

  for (int kt = 0; kt < 16; ++kt) {
    __syncthreads();
    #pragma unroll
    for (int p = 0; p < 2; ++p)
      gload_lds16(base + (size_t)(kt * 64 + p * 32 + skey) * 3072 + 1024 + h * 64 + sslot * 8,
                  (char*)Ks + p * 4096 + w * 1024);
    {
      bf16x4 vv[4];
      #pragma unroll
      for (int i = 0; i < 4; ++i)
        vv[i] = *reinterpret_cast<const bf16x4*>(
            base + (size_t)(kt * 64 + vk0 + i) * 3072 + 2048 + h * 64 + vd0);
      #pragma unroll
      for (int j = 0; j < 4; ++j) {
        int d = vd0 + j;
        bf16x4 o; o[0] = vv[0][j]; o[1] = vv[1][j]; o[2] = vv[2][j]; o[3] = vv[3][j];
        *reinterpret_cast<bf16x4*>(
            &Vt[d * 64 + ((vslot ^ (d & 7) ^ ((d >> 3) & 7)) * 8 + vhalf * 4)]) = o;
      }
    }
    __syncthreads();

    #pragma unroll
    for (int ktile = 0; ktile < 2; ++ktile) {
      f32x16 s = {};
      const int key = ktile * 32 + l31;
      #pragma unroll
      for (int st = 0; st < 4; ++st) {
        const int slot = (2 * st + hi) ^ (key & 7);
        bf16x8 kf = *reinterpret_cast<const bf16x8*>(&Ks[key * 64 + slot * 8]);
        s = __builtin_amdgcn_mfma_f32_32x32x16_bf16(kf, qf[st], s, 0, 0, 0);
      }
      #pragma unroll
      for (int gq = 0; gq < 4; ++gq) {
        bf16x4 pb;
        #pragma unroll
        for (int j2 = 0; j2 < 4; ++j2) {
          float pv = __builtin_amdgcn_exp2f(s[4 * gq + j2]);
          pb[j2] = (bf16)pv;
        }
        const int chunk = ktile * 4 + gq;
        *reinterpret_cast<bf16x4*>(
            &Pl[w][l31 * 64 + ((chunk ^ (l31 & 7)) * 8 + hi * 4)]) = pb;
      }
    }

    const int d7x0 = (l31 & 7) ^ (l31 >> 3);
    const int d7x1 = d7x0 ^ 4;
    #pragma unroll
    for (int st = 0; st < 4; ++st) {
      const int cs = 2 * st + hi;
      bf16x8 pa  = *reinterpret_cast<const bf16x8*>(
          &Pl[w][l31 * 64 + ((cs ^ (l31 & 7)) * 8)]);
      accS = __builtin_amdgcn_mfma_f32_32x32x16_bf16(pa, onesf, accS, 0, 0, 0);
      bf16x8 vf0 = *reinterpret_cast<const bf16x8*>(
          &Vt[l31 * 64 + ((cs ^ d7x0) * 8)]);
      acc0 = __builtin_amdgcn_mfma_f32_32x32x16_bf16(pa, vf0, acc0, 0, 0, 0);
      bf16x8 vf1 = *reinterpret_cast<const bf16x8*>(
          &Vt[(32 + l31) * 64 + ((cs ^ d7x1) * 8)]);
      acc1 = __builtin_amdgcn_mfma_f32_32x32x16_bf16(pa, vf1, acc1, 0, 0, 0);
    }
  }

  #pragma unroll
  for (int reg = 0; reg < 16; ++reg) {
    int q_r = (reg & 3) + 8 * (reg >> 2) + 4 * hi;
    float rinv = 1.0f / accS[reg];
    size_t rowoff = ((size_t)b * 1024 + qrow0 + q_r) * 1024 + h * 64;
    aout[rowoff + l31]      = (bf16)(acc0[reg] * rinv);
    aout[rowoff + 32 + l31] = (bf16)(acc1[reg] * rinv);
  }
}

// ---------------- launch ----------------

extern "C" void kernel_launch(void* const* d_in, const int* in_sizes, int n_in,
                              void* d_out, int out_size, void* d_ws, size_t ws_size,
                              hipStream_t stream) {
  const float* x     = (const float*)d_in[0];   // [8,1024,1024]
  const float* w_in  = (const float*)d_in[1];   // [1024,3072]
  const float* w_out = (const float*)d_in[2];   // [1024,1024]
  const float* b_out = (const float*)d_in[3];   // [1024]
  float* out = (float*)d_out;                   // [8,1024,1024] fp32

  bf16* xb    = (bf16*)d_ws;                         // 8192*1024
  bf16* wint  = xb    + (size_t)8192 * 1024;         // 3072*1024  (w_in^T)
  bf16* woutt = wint  + (size_t)3072 * 1024;         // 1024*1024  (w_out^T)
  bf16* qkv   = woutt + (size_t)1024 * 1024;         // 8192*3072
  bf16* ao    = qkv   + (size_t)8192 * 3072;         // 8192*1024

  cvt_f32_to_bf16<<<8192, 256, 0, stream>>>(x, xb, 8192 * 1024);
  transpose_cvt<<<dim3(96, 32), dim3(32, 8), 0, stream>>>(w_in,  wint,  1024, 3072);
  transpose_cvt<<<dim3(32, 32), dim3(32, 8), 0, stream>>>(w_out, woutt, 1024, 1024);

  // qkv = x @ w_in   (bf16 out) - 256^2 8-phase, 384 blocks (12x32)
  gemm_abt8<bf16, false><<<dim3(384), 512, 0, stream>>>(xb, wint, nullptr, qkv, 8192, 3072, 1024);

  // fused attention -> ao (bf16, [token][h*64+d])
  attn_fused<<<1024, 256, 0, stream>>>(qkv, ao);

  // out = ao @ w_out + b_out   (fp32 out) - 128^2 (N too small for 256^2 grid)
  gemm_abt<float, true><<<dim3(8, 64), 256, 0, stream>>>(ao, woutt, b_out, out, 8192, 1024, 1024);
}